// Round 10
// baseline (572.519 us; speedup 1.0000x reference)
//
#include <hip/hip_runtime.h>
#include <hip/hip_fp16.h>

#define N_NODES 50000
#define N_EDGES 800000
#define D 128
#define N_GRAPHS 64
#define NEG_SLOPE 0.01f
#define POOL_PARTS 8
#define ELLW 32      // 32 ushort slots = 64 B = exactly one cache line per node
#define OVF_CAP 8192 // overflow pairs; expected usage ~30

// ---------------- ELL build: 4 edges per thread, one-line rows + overflow ----------------
#define FILL_T 200000  // N_EDGES/4
__global__ __launch_bounds__(256) void k_fill(const int* __restrict__ src, const int* __restrict__ dst,
                                              int* __restrict__ cnti, unsigned short* __restrict__ ell,
                                              int2* __restrict__ ovf, int* __restrict__ ocnt) {
    int t = blockIdx.x * 256 + threadIdx.x;
    if (t >= FILL_T) return;
    int d_[4], s_[4];
#pragma unroll
    for (int k = 0; k < 4; k++) {
        d_[k] = dst[t + k * FILL_T];
        s_[k] = src[t + k * FILL_T];
    }
    int p_[4];
#pragma unroll
    for (int k = 0; k < 4; k++) p_[k] = atomicAdd(&cnti[d_[k]], 1);
#pragma unroll
    for (int k = 0; k < 4; k++) {
        if (p_[k] < ELLW) {
            ell[(size_t)d_[k] * ELLW + p_[k]] = (unsigned short)s_[k];
        } else {
            int o = atomicAdd(ocnt, 1);
            if (o < OVF_CAP) ovf[o] = make_int2(d_[k], s_[k]);
        }
    }
}

// ---------------- GEMM: Hs[N,128](fp16) = (x @ W) * rsqrt(cnt[row]+1) ----------------
#define BM 64
#define BK 32
#define XSTRIDE 36
__global__ __launch_bounds__(256) void k_gemm(const float* __restrict__ x, const float* __restrict__ W,
                                              const int* __restrict__ cnt, __half* __restrict__ h) {
    __shared__ float Xl[BM * XSTRIDE];
    __shared__ float Wl[BK * D];
    const int tid = threadIdx.x;
    const int row0 = blockIdx.x * BM;
    const int ty4 = (tid >> 4) * 4;
    const int tx4 = (tid & 15) * 4;

    float2 acc[4][4];
#pragma unroll
    for (int r = 0; r < 4; r++)
#pragma unroll
        for (int c = 0; c < 4; c++) acc[r][c] = make_float2(0.f, 0.f);

    for (int kb = 0; kb < D; kb += BK) {
#pragma unroll
        for (int i = 0; i < 2; i++) {
            int i2 = tid + 256 * i;
            int r = i2 >> 3, kg = i2 & 7;
            float4 xv = make_float4(0.f, 0.f, 0.f, 0.f);
            if (row0 + r < N_NODES) xv = *(const float4*)(x + (size_t)(row0 + r) * D + kb + kg * 4);
            *(float4*)&Xl[r * XSTRIDE + kg * 4] = xv;
        }
#pragma unroll
        for (int i = 0; i < 4; i++) {
            int i2 = tid + 256 * i;
            ((float4*)Wl)[i2] = ((const float4*)W)[(size_t)kb * 32 + i2];
        }
        __syncthreads();
#pragma unroll
        for (int k4 = 0; k4 < BK; k4 += 4) {
            float a_[4][4];
#pragma unroll
            for (int r = 0; r < 4; r++) {
                float4 t = *(const float4*)&Xl[(ty4 + r) * XSTRIDE + k4];
                a_[r][0] = t.x; a_[r][1] = t.y; a_[r][2] = t.z; a_[r][3] = t.w;
            }
#pragma unroll
            for (int kk = 0; kk < 4; kk++) {
                float4 b0 = *(const float4*)&Wl[(k4 + kk) * D + tx4];
                float4 b1 = *(const float4*)&Wl[(k4 + kk) * D + tx4 + 64];
                float bv[8] = {b0.x, b0.y, b0.z, b0.w, b1.x, b1.y, b1.z, b1.w};
#pragma unroll
                for (int r = 0; r < 4; r++)
#pragma unroll
                    for (int c = 0; c < 4; c++) {
                        acc[r][c].x = fmaf(a_[r][kk], bv[c], acc[r][c].x);
                        acc[r][c].y = fmaf(a_[r][kk], bv[c + 4], acc[r][c].y);
                    }
            }
        }
        __syncthreads();
    }
    // acc[r][c].x -> column tx4+c ; acc[r][c].y -> column tx4+64+c
#pragma unroll
    for (int r = 0; r < 4; r++) {
        int row = row0 + ty4 + r;
        if (row < N_NODES) {
            float di = rsqrtf((float)cnt[row] + 1.0f);
            union { __half2 h2[2]; float2 f2; } u0, u1;
            u0.h2[0] = __floats2half2_rn(acc[r][0].x * di, acc[r][1].x * di);
            u0.h2[1] = __floats2half2_rn(acc[r][2].x * di, acc[r][3].x * di);
            u1.h2[0] = __floats2half2_rn(acc[r][0].y * di, acc[r][1].y * di);
            u1.h2[1] = __floats2half2_rn(acc[r][2].y * di, acc[r][3].y * di);
            *(float2*)(h + (size_t)row * D + tx4) = u0.f2;
            *(float2*)(h + (size_t)row * D + tx4 + 64) = u1.f2;
        }
    }
}

// ---------------- ELL aggregation: one wave per dst node, 8 fp16 gather chains ----------------
__global__ __launch_bounds__(256) void k_agg(const int* __restrict__ cnt, const unsigned short* __restrict__ ell,
                                             const int2* __restrict__ ovf, const int* __restrict__ ocnt,
                                             const __half* __restrict__ Hs, const float* __restrict__ bias,
                                             float* __restrict__ out) {
    int lane = threadIdx.x & 63;
    int node = __builtin_amdgcn_readfirstlane(blockIdx.x * 4 + (threadIdx.x >> 6));
    int n = cnt[node];
    int nc = min(n, ELLW);
    const unsigned short* __restrict__ ep = ell + (size_t)node * ELLW;
    const __half2* __restrict__ H2 = (const __half2*)Hs;
    float2 acc[8];
    acc[0] = __half22float2(H2[(size_t)node * 64 + lane]);  // self term (already dinv-scaled)
#pragma unroll
    for (int i = 1; i < 8; i++) acc[i] = make_float2(0.f, 0.f);
    for (int j = 0; j < nc; j += 8) {
        int s[8]; float w[8];
#pragma unroll
        for (int i = 0; i < 8; i++) {
            bool v = (j + i) < nc;
            s[i] = v ? (int)ep[j + i] : 0;
            w[i] = v ? 1.0f : 0.0f;
        }
#pragma unroll
        for (int i = 0; i < 8; i++) {
            float2 hv = __half22float2(H2[(size_t)s[i] * 64 + lane]);
            acc[i].x = fmaf(w[i], hv.x, acc[i].x);
            acc[i].y = fmaf(w[i], hv.y, acc[i].y);
        }
    }
    if (n > ELLW) {  // rare: scan overflow list (expected ~30 entries total)
        int oc = min(*ocnt, OVF_CAP);
        for (int o = 0; o < oc; o++) {
            int2 p = ovf[o];
            if (p.x == node) {
                float2 hv = __half22float2(H2[(size_t)p.y * 64 + lane]);
                acc[0].x += hv.x; acc[0].y += hv.y;
            }
        }
    }
    float sx = ((acc[0].x + acc[1].x) + (acc[2].x + acc[3].x)) + ((acc[4].x + acc[5].x) + (acc[6].x + acc[7].x));
    float sy = ((acc[0].y + acc[1].y) + (acc[2].y + acc[3].y)) + ((acc[4].y + acc[5].y) + (acc[6].y + acc[7].y));
    float di = rsqrtf((float)n + 1.0f);
    float2 b = ((const float2*)bias)[lane];
    float vx = sx * di + b.x;
    float vy = sy * di + b.y;
    vx = vx > 0.0f ? vx : NEG_SLOPE * vx;
    vy = vy > 0.0f ? vy : NEG_SLOPE * vy;
    float2 r; r.x = vx; r.y = vy;
    ((float2*)out)[(size_t)node * 64 + lane] = r;
}

// ---------------- mean pool: per-(graph,part) partials, no atomics ----------------
__device__ __forceinline__ int lower_bound_i(const int* __restrict__ arr, int n, int key) {
    int lo = 0, hi = n;
    while (lo < hi) {
        int mid = (lo + hi) >> 1;
        if (arr[mid] < key) lo = mid + 1; else hi = mid;
    }
    return lo;
}

__global__ __launch_bounds__(256) void k_pool(const float* __restrict__ h, const int* __restrict__ batch,
                                              float* __restrict__ pp, float* __restrict__ cnt) {
    int g = blockIdx.x;
    int part = blockIdx.y;
    int lo = lower_bound_i(batch, N_NODES, g);
    int hi = lower_bound_i(batch, N_NODES, g + 1);
    int num = hi - lo;
    if (part == 0 && threadIdx.x == 0) cnt[g] = (float)num;
    int chunk = (num + POOL_PARTS - 1) / POOL_PARTS;
    int a = lo + part * chunk;
    int b = min(a + chunk, hi);
    int c = threadIdx.x & 127;
    int sub = threadIdx.x >> 7;
    float acc = 0.0f;
    for (int node = a + sub; node < b; node += 2) acc += h[(size_t)node * D + c];
    __shared__ float tmp[256];
    tmp[threadIdx.x] = acc;
    __syncthreads();
    if (sub == 0) pp[((size_t)g * POOL_PARTS + part) * D + c] = tmp[threadIdx.x] + tmp[threadIdx.x + 128];
}

// ---------------- final MLP (reduces pool parts) ----------------
__global__ __launch_bounds__(128) void k_mlp(const float* __restrict__ pp1, const float* __restrict__ pp2,
                                             const float* __restrict__ cnt1, const float* __restrict__ cnt2,
                                             const float* __restrict__ lin1W, const float* __restrict__ lin1b,
                                             const float* __restrict__ lin2W, const float* __restrict__ lin2b,
                                             float* __restrict__ out) {
    int g = blockIdx.x;
    int c = threadIdx.x;
    __shared__ float cat[2 * D];
    float s1 = 0.f, s2 = 0.f;
#pragma unroll
    for (int p = 0; p < POOL_PARTS; p++) {
        s1 += pp1[((size_t)g * POOL_PARTS + p) * D + c];
        s2 += pp2[((size_t)g * POOL_PARTS + p) * D + c];
    }
    cat[c] = s1 / fmaxf(cnt1[g], 1.0f);
    cat[c + D] = s2 / fmaxf(cnt2[g], 1.0f);
    __syncthreads();
    float acc = lin1b[c];
#pragma unroll 8
    for (int k = 0; k < 2 * D; k++) acc += cat[k] * lin1W[k * D + c];
    acc = fmaxf(acc, 0.0f);
    float v = acc * lin2W[c];
#pragma unroll
    for (int off = 32; off > 0; off >>= 1) v += __shfl_down(v, off, 64);
    __shared__ float wsum[2];
    if ((c & 63) == 0) wsum[c >> 6] = v;
    __syncthreads();
    if (c == 0) out[g] = wsum[0] + wsum[1] + lin2b[0];
}

extern "C" void kernel_launch(void* const* d_in, const int* in_sizes, int n_in,
                              void* d_out, int out_size, void* d_ws, size_t ws_size,
                              hipStream_t stream) {
    const float* xs[2]      = {(const float*)d_in[0], (const float*)d_in[3]};
    const int*   eis[2]     = {(const int*)d_in[1], (const int*)d_in[4]};
    const int*   batches[2] = {(const int*)d_in[2], (const int*)d_in[5]};
    const float* W0[2] = {(const float*)d_in[6],  (const float*)d_in[10]};
    const float* b0[2] = {(const float*)d_in[7],  (const float*)d_in[11]};
    const float* W1[2] = {(const float*)d_in[8],  (const float*)d_in[12]};
    const float* b1[2] = {(const float*)d_in[9],  (const float*)d_in[13]};
    const float* lin1W = (const float*)d_in[14];
    const float* lin1b = (const float*)d_in[15];
    const float* lin2W = (const float*)d_in[16];
    const float* lin2b = (const float*)d_in[17];
    float* out = (float*)d_out;

    float* ws = (float*)d_ws;
    float*  ACT  = ws;                                   // 6.4M floats
    __half* H    = (__half*)(ACT + (size_t)N_NODES * D); // 6.4M halves
    int*    cnti = (int*)(H + (size_t)N_NODES * D);      // 50000
    int*    ocnt = cnti + N_NODES;                       // 1 (memset together with cnti)
    int2*   ovf  = (int2*)(ocnt + 1);                    // OVF_CAP pairs
    unsigned short* ell = (unsigned short*)(ovf + OVF_CAP);  // 50000*32 ushorts
    float*  pp1  = (float*)(ell + (size_t)N_NODES * ELLW);
    float*  pp2  = pp1 + (size_t)N_GRAPHS * POOL_PARTS * D;
    float*  cnt1 = pp2 + (size_t)N_GRAPHS * POOL_PARTS * D;
    float*  cnt2 = cnt1 + N_GRAPHS;
    float*  pps[2]  = {pp1, pp2};
    float*  cnts[2] = {cnt1, cnt2};

    dim3 b256(256);
    int fillBlocks = (FILL_T + 255) / 256;
    int gemmBlocks = (N_NODES + BM - 1) / BM;  // 782
    int aggBlocks  = N_NODES / 4;              // 12500

    for (int br = 0; br < 2; br++) {
        const int* srcp = eis[br];
        const int* dstp = eis[br] + N_EDGES;

        hipMemsetAsync(cnti, 0, (N_NODES + 1) * sizeof(int), stream);
        k_fill<<<fillBlocks, b256, 0, stream>>>(srcp, dstp, cnti, ell, ovf, ocnt);

        k_gemm<<<gemmBlocks, b256, 0, stream>>>(xs[br], W0[br], cnti, H);
        k_agg<<<aggBlocks, b256, 0, stream>>>(cnti, ell, ovf, ocnt, H, b0[br], ACT);
        k_gemm<<<gemmBlocks, b256, 0, stream>>>(ACT, W1[br], cnti, H);
        k_agg<<<aggBlocks, b256, 0, stream>>>(cnti, ell, ovf, ocnt, H, b1[br], ACT);

        k_pool<<<dim3(N_GRAPHS, POOL_PARTS), b256, 0, stream>>>(ACT, batches[br], pps[br], cnts[br]);
    }
    k_mlp<<<N_GRAPHS, dim3(128), 0, stream>>>(pp1, pp2, cnt1, cnt2, lin1W, lin1b, lin2W, lin2b, out);
}

// Round 11
// 512.628 us; speedup vs baseline: 1.1168x; 1.1168x over previous
//
#include <hip/hip_runtime.h>
#include <hip/hip_fp16.h>

#define N_NODES 50000
#define N_EDGES 800000
#define D 128
#define N_GRAPHS 64
#define NEG_SLOPE 0.01f
#define POOL_PARTS 8
#define ELLW 32      // 32 ushort slots = 64 B per node row
#define OVF_CAP 8192 // overflow pairs; expected usage ~30

typedef _Float16 half8 __attribute__((ext_vector_type(8)));
typedef _Float16 half4 __attribute__((ext_vector_type(4)));
typedef float f32x4 __attribute__((ext_vector_type(4)));

// ---------------- W transpose+cast prep: WtH[w][n*128+k] = (half)W[k*128+n] ----------------
__global__ __launch_bounds__(256) void k_prep(const float* __restrict__ Wa, const float* __restrict__ Wb,
                                              const float* __restrict__ Wc, const float* __restrict__ Wd,
                                              __half* __restrict__ WtH) {
    const float* Ws[4] = {Wa, Wb, Wc, Wd};
    const float* W = Ws[blockIdx.x];
    __half* o = WtH + (size_t)blockIdx.x * 16384;
    int t = threadIdx.x;
    for (int r = 0; r < 64; r++) {
        int e = r * 256 + t;
        int k = e >> 7, n = e & 127;
        o[n * 128 + k] = __float2half(W[k * 128 + n]);
    }
}

// ---------------- ELL build: 4 edges per thread, overflow list for deg>32 ----------------
#define FILL_T 200000  // N_EDGES/4
__global__ __launch_bounds__(256) void k_fill(const int* __restrict__ src, const int* __restrict__ dst,
                                              int* __restrict__ cnti, unsigned short* __restrict__ ell,
                                              int2* __restrict__ ovf, int* __restrict__ ocnt) {
    int t = blockIdx.x * 256 + threadIdx.x;
    if (t >= FILL_T) return;
    int d_[4], s_[4];
#pragma unroll
    for (int k = 0; k < 4; k++) {
        d_[k] = dst[t + k * FILL_T];
        s_[k] = src[t + k * FILL_T];
    }
    int p_[4];
#pragma unroll
    for (int k = 0; k < 4; k++) p_[k] = atomicAdd(&cnti[d_[k]], 1);
#pragma unroll
    for (int k = 0; k < 4; k++) {
        if (p_[k] < ELLW) {
            ell[(size_t)d_[k] * ELLW + p_[k]] = (unsigned short)s_[k];
        } else {
            int o = atomicAdd(ocnt, 1);
            if (o < OVF_CAP) ovf[o] = make_int2(d_[k], s_[k]);
        }
    }
}

// ---------------- MFMA GEMM: H[N,128](fp16) = (x @ W) * rsqrt(cnt+1) ----------------
// 256 thr = 4 waves; block tile M=64, N=128, K=128. Wave: rows w*16..+15, 8 col-tiles.
// LDS stride 136 halves (pad 8): frag ds_read_b128 is 2-way-conflict (free).
#define XS 136
template <bool FP16IN>
__global__ __launch_bounds__(256) void k_gemm(const void* __restrict__ xin, const __half* __restrict__ WtH,
                                              const int* __restrict__ cnt, __half* __restrict__ h) {
    __shared__ _Float16 Xl[64 * XS];
    __shared__ _Float16 Wt[128 * XS];
    const int tid = threadIdx.x;
    const int w = tid >> 6, lane = tid & 63;
    const int quad = lane >> 4, l16 = lane & 15;
    const int row0 = blockIdx.x * 64;

    // stage Wt (fp16, already transposed): 128 rows x 16 uint4
#pragma unroll
    for (int i = 0; i < 8; i++) {
        int i2 = tid + 256 * i;
        int r = i2 >> 4, cg = i2 & 15;
        *(uint4*)&Wt[r * XS + cg * 8] = ((const uint4*)WtH)[i2];
    }
    // stage X with cast
    if (FP16IN) {
        const __half* x = (const __half*)xin;
#pragma unroll
        for (int i = 0; i < 4; i++) {
            int i2 = tid + 256 * i;
            int r = i2 >> 4, cg = i2 & 15;
            uint4 v = make_uint4(0, 0, 0, 0);
            if (row0 + r < N_NODES) v = ((const uint4*)(x + (size_t)(row0 + r) * D))[cg];
            *(uint4*)&Xl[r * XS + cg * 8] = v;
        }
    } else {
        const float* x = (const float*)xin;
#pragma unroll
        for (int i = 0; i < 8; i++) {
            int i2 = tid + 256 * i;
            int r = i2 >> 5, f4 = i2 & 31;
            float4 v = make_float4(0.f, 0.f, 0.f, 0.f);
            if (row0 + r < N_NODES) v = *(const float4*)((const float*)x + (size_t)(row0 + r) * D + f4 * 4);
            half4 hv;
            hv[0] = (_Float16)v.x; hv[1] = (_Float16)v.y; hv[2] = (_Float16)v.z; hv[3] = (_Float16)v.w;
            *(half4*)&Xl[r * XS + f4 * 4] = hv;
        }
    }
    __syncthreads();

    // A fragments: A[m=l16][k=quad*8+j], hoisted over all 4 K-chunks
    half8 a[4];
#pragma unroll
    for (int kb = 0; kb < 4; kb++)
        a[kb] = *(const half8*)&Xl[(w * 16 + l16) * XS + kb * 32 + quad * 8];

    // dinv for this lane's 4 output rows (row = quad*4 + reg within tile)
    const int rbase = row0 + w * 16 + quad * 4;
    float di[4];
#pragma unroll
    for (int reg = 0; reg < 4; reg++) {
        int r = rbase + reg;
        di[reg] = (r < N_NODES) ? rsqrtf((float)cnt[r] + 1.0f) : 0.0f;
    }

#pragma unroll
    for (int ct = 0; ct < 8; ct++) {
        f32x4 acc = {0.f, 0.f, 0.f, 0.f};
#pragma unroll
        for (int kb = 0; kb < 4; kb++) {
            half8 b = *(const half8*)&Wt[(ct * 16 + l16) * XS + kb * 32 + quad * 8];
            acc = __builtin_amdgcn_mfma_f32_16x16x32_f16(a[kb], b, acc, 0, 0, 0);
        }
        int col = ct * 16 + l16;
#pragma unroll
        for (int reg = 0; reg < 4; reg++) {
            int r = rbase + reg;
            if (r < N_NODES) h[(size_t)r * D + col] = __float2half(acc[reg] * di[reg]);
        }
    }
}

// ---------------- ELL aggregation: one wave per dst node, 8 fp16 gather chains ----------------
// out(fp16)[d] = leaky( dinv[d] * (H[d] + sum H[src]) + bias )
__global__ __launch_bounds__(256) void k_agg(const int* __restrict__ cnt, const unsigned short* __restrict__ ell,
                                             const int2* __restrict__ ovf, const int* __restrict__ ocnt,
                                             const __half* __restrict__ Hs, const float* __restrict__ bias,
                                             __half* __restrict__ out) {
    int lane = threadIdx.x & 63;
    int node = __builtin_amdgcn_readfirstlane(blockIdx.x * 4 + (threadIdx.x >> 6));
    int n = cnt[node];
    int nc = min(n, ELLW);
    const unsigned short* __restrict__ ep = ell + (size_t)node * ELLW;
    const __half2* __restrict__ H2 = (const __half2*)Hs;
    float2 acc[8];
    acc[0] = __half22float2(H2[(size_t)node * 64 + lane]);  // self term (already dinv-scaled)
#pragma unroll
    for (int i = 1; i < 8; i++) acc[i] = make_float2(0.f, 0.f);
    for (int j = 0; j < nc; j += 8) {
        int s[8]; float w[8];
#pragma unroll
        for (int i = 0; i < 8; i++) {
            bool v = (j + i) < nc;
            s[i] = v ? (int)ep[j + i] : 0;
            w[i] = v ? 1.0f : 0.0f;
        }
#pragma unroll
        for (int i = 0; i < 8; i++) {
            float2 hv = __half22float2(H2[(size_t)s[i] * 64 + lane]);
            acc[i].x = fmaf(w[i], hv.x, acc[i].x);
            acc[i].y = fmaf(w[i], hv.y, acc[i].y);
        }
    }
    if (n > ELLW) {  // rare: scan overflow list (expected ~30 entries total)
        int oc = min(*ocnt, OVF_CAP);
        for (int o = 0; o < oc; o++) {
            int2 p = ovf[o];
            if (p.x == node) {
                float2 hv = __half22float2(H2[(size_t)p.y * 64 + lane]);
                acc[0].x += hv.x; acc[0].y += hv.y;
            }
        }
    }
    float sx = ((acc[0].x + acc[1].x) + (acc[2].x + acc[3].x)) + ((acc[4].x + acc[5].x) + (acc[6].x + acc[7].x));
    float sy = ((acc[0].y + acc[1].y) + (acc[2].y + acc[3].y)) + ((acc[4].y + acc[5].y) + (acc[6].y + acc[7].y));
    float dv = rsqrtf((float)n + 1.0f);
    float2 b = ((const float2*)bias)[lane];
    float vx = sx * dv + b.x;
    float vy = sy * dv + b.y;
    vx = vx > 0.0f ? vx : NEG_SLOPE * vx;
    vy = vy > 0.0f ? vy : NEG_SLOPE * vy;
    ((__half2*)out)[(size_t)node * 64 + lane] = __floats2half2_rn(vx, vy);
}

// ---------------- mean pool (fp16 in): per-(graph,part) float partials ----------------
__device__ __forceinline__ int lower_bound_i(const int* __restrict__ arr, int n, int key) {
    int lo = 0, hi = n;
    while (lo < hi) {
        int mid = (lo + hi) >> 1;
        if (arr[mid] < key) lo = mid + 1; else hi = mid;
    }
    return lo;
}

__global__ __launch_bounds__(256) void k_pool(const __half* __restrict__ h, const int* __restrict__ batch,
                                              float* __restrict__ pp, float* __restrict__ cnt) {
    int g = blockIdx.x;
    int part = blockIdx.y;
    int lo = lower_bound_i(batch, N_NODES, g);
    int hi = lower_bound_i(batch, N_NODES, g + 1);
    int num = hi - lo;
    if (part == 0 && threadIdx.x == 0) cnt[g] = (float)num;
    int chunk = (num + POOL_PARTS - 1) / POOL_PARTS;
    int a = lo + part * chunk;
    int b = min(a + chunk, hi);
    int c2 = threadIdx.x & 63;   // column pair
    int sub = threadIdx.x >> 6;  // 0..3
    const __half2* __restrict__ h2 = (const __half2*)h;
    float2 acc = make_float2(0.f, 0.f);
    for (int node = a + sub; node < b; node += 4) {
        float2 v = __half22float2(h2[(size_t)node * 64 + c2]);
        acc.x += v.x; acc.y += v.y;
    }
    __shared__ float2 tmp[256];
    tmp[threadIdx.x] = acc;
    __syncthreads();
    if (sub == 0) {
        float2 s;
        s.x = tmp[c2].x + tmp[c2 + 64].x + tmp[c2 + 128].x + tmp[c2 + 192].x;
        s.y = tmp[c2].y + tmp[c2 + 64].y + tmp[c2 + 128].y + tmp[c2 + 192].y;
        ((float2*)pp)[((size_t)g * POOL_PARTS + part) * 64 + c2] = s;
    }
}

// ---------------- final MLP (reduces pool parts) ----------------
__global__ __launch_bounds__(128) void k_mlp(const float* __restrict__ pp1, const float* __restrict__ pp2,
                                             const float* __restrict__ cnt1, const float* __restrict__ cnt2,
                                             const float* __restrict__ lin1W, const float* __restrict__ lin1b,
                                             const float* __restrict__ lin2W, const float* __restrict__ lin2b,
                                             float* __restrict__ out) {
    int g = blockIdx.x;
    int c = threadIdx.x;
    __shared__ float cat[2 * D];
    float s1 = 0.f, s2 = 0.f;
#pragma unroll
    for (int p = 0; p < POOL_PARTS; p++) {
        s1 += pp1[((size_t)g * POOL_PARTS + p) * D + c];
        s2 += pp2[((size_t)g * POOL_PARTS + p) * D + c];
    }
    cat[c] = s1 / fmaxf(cnt1[g], 1.0f);
    cat[c + D] = s2 / fmaxf(cnt2[g], 1.0f);
    __syncthreads();
    float acc = lin1b[c];
#pragma unroll 8
    for (int k = 0; k < 2 * D; k++) acc += cat[k] * lin1W[k * D + c];
    acc = fmaxf(acc, 0.0f);
    float v = acc * lin2W[c];
#pragma unroll
    for (int off = 32; off > 0; off >>= 1) v += __shfl_down(v, off, 64);
    __shared__ float wsum[2];
    if ((c & 63) == 0) wsum[c >> 6] = v;
    __syncthreads();
    if (c == 0) out[g] = wsum[0] + wsum[1] + lin2b[0];
}

extern "C" void kernel_launch(void* const* d_in, const int* in_sizes, int n_in,
                              void* d_out, int out_size, void* d_ws, size_t ws_size,
                              hipStream_t stream) {
    const float* xs[2]      = {(const float*)d_in[0], (const float*)d_in[3]};
    const int*   eis[2]     = {(const int*)d_in[1], (const int*)d_in[4]};
    const int*   batches[2] = {(const int*)d_in[2], (const int*)d_in[5]};
    const float* W0[2] = {(const float*)d_in[6],  (const float*)d_in[10]};
    const float* b0[2] = {(const float*)d_in[7],  (const float*)d_in[11]};
    const float* W1[2] = {(const float*)d_in[8],  (const float*)d_in[12]};
    const float* b1[2] = {(const float*)d_in[9],  (const float*)d_in[13]};
    const float* lin1W = (const float*)d_in[14];
    const float* lin1b = (const float*)d_in[15];
    const float* lin2W = (const float*)d_in[16];
    const float* lin2b = (const float*)d_in[17];
    float* out = (float*)d_out;

    __half* WtH = (__half*)d_ws;                          // 4*16384 halves
    __half* ACT = WtH + 4 * 16384;                        // N*D halves
    __half* H   = ACT + (size_t)N_NODES * D;              // N*D halves
    int*    cnti = (int*)(H + (size_t)N_NODES * D);       // N ints
    int*    ocnt = cnti + N_NODES;                        // 1 (+1 pad)
    int2*   ovf  = (int2*)(cnti + N_NODES + 2);           // OVF_CAP pairs (8B aligned)
    unsigned short* ell = (unsigned short*)(ovf + OVF_CAP);  // N*ELLW ushorts
    float*  pp1  = (float*)(ell + (size_t)N_NODES * ELLW);
    float*  pp2  = pp1 + (size_t)N_GRAPHS * POOL_PARTS * D;
    float*  cnt1 = pp2 + (size_t)N_GRAPHS * POOL_PARTS * D;
    float*  cnt2 = cnt1 + N_GRAPHS;
    float*  pps[2]  = {pp1, pp2};
    float*  cnts[2] = {cnt1, cnt2};

    dim3 b256(256);
    int fillBlocks = (FILL_T + 255) / 256;
    int gemmBlocks = (N_NODES + 63) / 64;  // 782
    int aggBlocks  = N_NODES / 4;          // 12500

    // weight order: [br0 layer0, br0 layer1, br1 layer0, br1 layer1]
    k_prep<<<4, b256, 0, stream>>>(W0[0], W1[0], W0[1], W1[1], WtH);

    for (int br = 0; br < 2; br++) {
        const int* srcp = eis[br];
        const int* dstp = eis[br] + N_EDGES;

        hipMemsetAsync(cnti, 0, (N_NODES + 1) * sizeof(int), stream);
        k_fill<<<fillBlocks, b256, 0, stream>>>(srcp, dstp, cnti, ell, ovf, ocnt);

        k_gemm<false><<<gemmBlocks, b256, 0, stream>>>(xs[br], WtH + (size_t)(br * 2 + 0) * 16384, cnti, H);
        k_agg<<<aggBlocks, b256, 0, stream>>>(cnti, ell, ovf, ocnt, H, b0[br], ACT);
        k_gemm<true><<<gemmBlocks, b256, 0, stream>>>(ACT, WtH + (size_t)(br * 2 + 1) * 16384, cnti, H);
        k_agg<<<aggBlocks, b256, 0, stream>>>(cnti, ell, ovf, ocnt, H, b1[br], ACT);

        k_pool<<<dim3(N_GRAPHS, POOL_PARTS), b256, 0, stream>>>(ACT, batches[br], pps[br], cnts[br]);
    }
    k_mlp<<<N_GRAPHS, dim3(128), 0, stream>>>(pp1, pp2, cnt1, cnt2, lin1W, lin1b, lin2W, lin2b, out);
}

// Round 12
// 474.335 us; speedup vs baseline: 1.2070x; 1.0807x over previous
//
#include <hip/hip_runtime.h>
#include <hip/hip_fp16.h>

#define N_NODES 50000
#define N_EDGES 800000
#define D 128
#define N_GRAPHS 64
#define NEG_SLOPE 0.01f
#define POOL_PARTS 8
#define ELLW 32      // 32 ushort slots = 64 B per node row
#define OVF_CAP 8192 // overflow pairs; expected usage ~30

#define BUCKETS 196  // dst>>8 -> 196 buckets of 256 nodes
#define NPAD (BUCKETS * 256)  // 50176 padded node rows
#define EPB 4096     // edges per phase-A block
#define BCAP 5120    // per-bucket capacity (mean 4096, sigma 64 -> +16 sigma)

typedef _Float16 half8 __attribute__((ext_vector_type(8)));
typedef _Float16 half4 __attribute__((ext_vector_type(4)));
typedef float f32x4 __attribute__((ext_vector_type(4)));

// ---------------- W transpose+cast prep: WtH[w][n*128+k] = (half)W[k*128+n] ----------------
__global__ __launch_bounds__(256) void k_prep(const float* __restrict__ Wa, const float* __restrict__ Wb,
                                              const float* __restrict__ Wc, const float* __restrict__ Wd,
                                              __half* __restrict__ WtH) {
    const float* Ws[4] = {Wa, Wb, Wc, Wd};
    const float* W = Ws[blockIdx.x];
    __half* o = WtH + (size_t)blockIdx.x * 16384;
    int t = threadIdx.x;
    for (int r = 0; r < 64; r++) {
        int e = r * 256 + t;
        int k = e >> 7, n = e & 127;
        o[n * 128 + k] = __float2half(W[k * 128 + n]);
    }
}

// ---------------- Phase A: partition edges into dst-buckets (coalesced writes) ----------------
__global__ __launch_bounds__(256) void k_part(const int* __restrict__ src, const int* __restrict__ dst,
                                              int* __restrict__ gcnt, int2* __restrict__ bucketed) {
    __shared__ int bcnt[BUCKETS];
    __shared__ int bofs[BUCKETS];
    __shared__ int gbase[BUCKETS];
    __shared__ int2 stage[EPB];
    const int tid = threadIdx.x;
    const int base = blockIdx.x * EPB;
    for (int b = tid; b < BUCKETS; b += 256) bcnt[b] = 0;
    __syncthreads();
    int d_[16], s_[16], p_[16];
#pragma unroll
    for (int k = 0; k < 16; k++) {
        int i = base + k * 256 + tid;
        bool v = i < N_EDGES;
        d_[k] = v ? dst[i] : -1;
        s_[k] = v ? src[i] : 0;
        p_[k] = 0;
        if (v) p_[k] = atomicAdd(&bcnt[d_[k] >> 8], 1);
    }
    __syncthreads();
    if (tid == 0) {
        int run = 0;
        for (int b = 0; b < BUCKETS; b++) { bofs[b] = run; run += bcnt[b]; }
    }
    __syncthreads();
    if (tid < BUCKETS) gbase[tid] = atomicAdd(&gcnt[tid], bcnt[tid]);
    __syncthreads();
#pragma unroll
    for (int k = 0; k < 16; k++) {
        if (d_[k] >= 0) stage[bofs[d_[k] >> 8] + p_[k]] = make_int2(d_[k], s_[k]);
    }
    __syncthreads();
    int total = bofs[BUCKETS - 1] + bcnt[BUCKETS - 1];
    for (int i = tid; i < total; i += 256) {
        int2 e = stage[i];
        int b = e.x >> 8;
        int dest = gbase[b] + (i - bofs[b]);
        if (dest < BCAP) bucketed[(size_t)b * BCAP + dest] = e;  // overflow impossible (+16 sigma)
    }
}

// ---------------- Phase B: build ELL tile per bucket in LDS, write coalesced ----------------
__global__ __launch_bounds__(256) void k_build(const int* __restrict__ gcnt, const int2* __restrict__ bucketed,
                                               int* __restrict__ cnti, unsigned short* __restrict__ ell,
                                               int2* __restrict__ ovf, int* __restrict__ ocnt) {
    __shared__ unsigned short lell[256 * ELLW];  // 16 KB
    __shared__ int lcnt[256];
    const int b = blockIdx.x, tid = threadIdx.x;
    lcnt[tid] = 0;
    __syncthreads();
    int nb = min(gcnt[b], BCAP);
    const int2* __restrict__ bp = bucketed + (size_t)b * BCAP;
    for (int i = tid; i < nb; i += 256) {
        int2 e = bp[i];
        int dl = e.x & 255;
        int p = atomicAdd(&lcnt[dl], 1);
        if (p < ELLW) {
            lell[dl * ELLW + p] = (unsigned short)e.y;
        } else {
            int o = atomicAdd(ocnt, 1);
            if (o < OVF_CAP) ovf[o] = e;
        }
    }
    __syncthreads();
    cnti[b * 256 + tid] = lcnt[tid];
    uint4* eg = (uint4*)(ell + (size_t)b * 256 * ELLW);
    const uint4* el = (const uint4*)lell;
    for (int i = tid; i < 256 * ELLW * 2 / 16; i += 256) eg[i] = el[i];
}

// ---------------- MFMA GEMM: H[N,128](fp16) = (x @ W) * rsqrt(cnt+1) ----------------
#define XS 136
template <bool FP16IN>
__global__ __launch_bounds__(256) void k_gemm(const void* __restrict__ xin, const __half* __restrict__ WtH,
                                              const int* __restrict__ cnt, __half* __restrict__ h) {
    __shared__ _Float16 Xl[64 * XS];
    __shared__ _Float16 Wt[128 * XS];
    const int tid = threadIdx.x;
    const int w = tid >> 6, lane = tid & 63;
    const int quad = lane >> 4, l16 = lane & 15;
    const int row0 = blockIdx.x * 64;

#pragma unroll
    for (int i = 0; i < 8; i++) {
        int i2 = tid + 256 * i;
        int r = i2 >> 4, cg = i2 & 15;
        *(uint4*)&Wt[r * XS + cg * 8] = ((const uint4*)WtH)[i2];
    }
    if (FP16IN) {
        const __half* x = (const __half*)xin;
#pragma unroll
        for (int i = 0; i < 4; i++) {
            int i2 = tid + 256 * i;
            int r = i2 >> 4, cg = i2 & 15;
            uint4 v = make_uint4(0, 0, 0, 0);
            if (row0 + r < N_NODES) v = ((const uint4*)(x + (size_t)(row0 + r) * D))[cg];
            *(uint4*)&Xl[r * XS + cg * 8] = v;
        }
    } else {
        const float* x = (const float*)xin;
#pragma unroll
        for (int i = 0; i < 8; i++) {
            int i2 = tid + 256 * i;
            int r = i2 >> 5, f4 = i2 & 31;
            float4 v = make_float4(0.f, 0.f, 0.f, 0.f);
            if (row0 + r < N_NODES) v = *(const float4*)((const float*)x + (size_t)(row0 + r) * D + f4 * 4);
            half4 hv;
            hv[0] = (_Float16)v.x; hv[1] = (_Float16)v.y; hv[2] = (_Float16)v.z; hv[3] = (_Float16)v.w;
            *(half4*)&Xl[r * XS + f4 * 4] = hv;
        }
    }
    __syncthreads();

    half8 a[4];
#pragma unroll
    for (int kb = 0; kb < 4; kb++)
        a[kb] = *(const half8*)&Xl[(w * 16 + l16) * XS + kb * 32 + quad * 8];

    const int rbase = row0 + w * 16 + quad * 4;
    float di[4];
#pragma unroll
    for (int reg = 0; reg < 4; reg++) {
        int r = rbase + reg;
        di[reg] = (r < N_NODES) ? rsqrtf((float)cnt[r] + 1.0f) : 0.0f;
    }

#pragma unroll
    for (int ct = 0; ct < 8; ct++) {
        f32x4 acc = {0.f, 0.f, 0.f, 0.f};
#pragma unroll
        for (int kb = 0; kb < 4; kb++) {
            half8 b = *(const half8*)&Wt[(ct * 16 + l16) * XS + kb * 32 + quad * 8];
            acc = __builtin_amdgcn_mfma_f32_16x16x32_f16(a[kb], b, acc, 0, 0, 0);
        }
        int col = ct * 16 + l16;
#pragma unroll
        for (int reg = 0; reg < 4; reg++) {
            int r = rbase + reg;
            if (r < N_NODES) h[(size_t)r * D + col] = __float2half(acc[reg] * di[reg]);
        }
    }
}

// ---------------- ELL aggregation: one wave per dst node, 8 fp16 gather chains ----------------
__global__ __launch_bounds__(256) void k_agg(const int* __restrict__ cnt, const unsigned short* __restrict__ ell,
                                             const int2* __restrict__ ovf, const int* __restrict__ ocnt,
                                             const __half* __restrict__ Hs, const float* __restrict__ bias,
                                             __half* __restrict__ out) {
    int lane = threadIdx.x & 63;
    int node = __builtin_amdgcn_readfirstlane(blockIdx.x * 4 + (threadIdx.x >> 6));
    int n = cnt[node];
    int nc = min(n, ELLW);
    const unsigned short* __restrict__ ep = ell + (size_t)node * ELLW;
    const __half2* __restrict__ H2 = (const __half2*)Hs;
    float2 acc[8];
    acc[0] = __half22float2(H2[(size_t)node * 64 + lane]);  // self term (already dinv-scaled)
#pragma unroll
    for (int i = 1; i < 8; i++) acc[i] = make_float2(0.f, 0.f);
    for (int j = 0; j < nc; j += 8) {
        int s[8]; float w[8];
#pragma unroll
        for (int i = 0; i < 8; i++) {
            bool v = (j + i) < nc;
            s[i] = v ? (int)ep[j + i] : 0;
            w[i] = v ? 1.0f : 0.0f;
        }
#pragma unroll
        for (int i = 0; i < 8; i++) {
            float2 hv = __half22float2(H2[(size_t)s[i] * 64 + lane]);
            acc[i].x = fmaf(w[i], hv.x, acc[i].x);
            acc[i].y = fmaf(w[i], hv.y, acc[i].y);
        }
    }
    if (n > ELLW) {
        int oc = min(*ocnt, OVF_CAP);
        for (int o = 0; o < oc; o++) {
            int2 p = ovf[o];
            if (p.x == node) {
                float2 hv = __half22float2(H2[(size_t)p.y * 64 + lane]);
                acc[0].x += hv.x; acc[0].y += hv.y;
            }
        }
    }
    float sx = ((acc[0].x + acc[1].x) + (acc[2].x + acc[3].x)) + ((acc[4].x + acc[5].x) + (acc[6].x + acc[7].x));
    float sy = ((acc[0].y + acc[1].y) + (acc[2].y + acc[3].y)) + ((acc[4].y + acc[5].y) + (acc[6].y + acc[7].y));
    float dv = rsqrtf((float)n + 1.0f);
    float2 b = ((const float2*)bias)[lane];
    float vx = sx * dv + b.x;
    float vy = sy * dv + b.y;
    vx = vx > 0.0f ? vx : NEG_SLOPE * vx;
    vy = vy > 0.0f ? vy : NEG_SLOPE * vy;
    ((__half2*)out)[(size_t)node * 64 + lane] = __floats2half2_rn(vx, vy);
}

// ---------------- mean pool (fp16 in): per-(graph,part) float partials ----------------
__device__ __forceinline__ int lower_bound_i(const int* __restrict__ arr, int n, int key) {
    int lo = 0, hi = n;
    while (lo < hi) {
        int mid = (lo + hi) >> 1;
        if (arr[mid] < key) lo = mid + 1; else hi = mid;
    }
    return lo;
}

__global__ __launch_bounds__(256) void k_pool(const __half* __restrict__ h, const int* __restrict__ batch,
                                              float* __restrict__ pp, float* __restrict__ cnt) {
    int g = blockIdx.x;
    int part = blockIdx.y;
    int lo = lower_bound_i(batch, N_NODES, g);
    int hi = lower_bound_i(batch, N_NODES, g + 1);
    int num = hi - lo;
    if (part == 0 && threadIdx.x == 0) cnt[g] = (float)num;
    int chunk = (num + POOL_PARTS - 1) / POOL_PARTS;
    int a = lo + part * chunk;
    int b = min(a + chunk, hi);
    int c2 = threadIdx.x & 63;
    int sub = threadIdx.x >> 6;
    const __half2* __restrict__ h2 = (const __half2*)h;
    float2 acc = make_float2(0.f, 0.f);
    for (int node = a + sub; node < b; node += 4) {
        float2 v = __half22float2(h2[(size_t)node * 64 + c2]);
        acc.x += v.x; acc.y += v.y;
    }
    __shared__ float2 tmp[256];
    tmp[threadIdx.x] = acc;
    __syncthreads();
    if (sub == 0) {
        float2 s;
        s.x = tmp[c2].x + tmp[c2 + 64].x + tmp[c2 + 128].x + tmp[c2 + 192].x;
        s.y = tmp[c2].y + tmp[c2 + 64].y + tmp[c2 + 128].y + tmp[c2 + 192].y;
        ((float2*)pp)[((size_t)g * POOL_PARTS + part) * 64 + c2] = s;
    }
}

// ---------------- final MLP (reduces pool parts) ----------------
__global__ __launch_bounds__(128) void k_mlp(const float* __restrict__ pp1, const float* __restrict__ pp2,
                                             const float* __restrict__ cnt1, const float* __restrict__ cnt2,
                                             const float* __restrict__ lin1W, const float* __restrict__ lin1b,
                                             const float* __restrict__ lin2W, const float* __restrict__ lin2b,
                                             float* __restrict__ out) {
    int g = blockIdx.x;
    int c = threadIdx.x;
    __shared__ float cat[2 * D];
    float s1 = 0.f, s2 = 0.f;
#pragma unroll
    for (int p = 0; p < POOL_PARTS; p++) {
        s1 += pp1[((size_t)g * POOL_PARTS + p) * D + c];
        s2 += pp2[((size_t)g * POOL_PARTS + p) * D + c];
    }
    cat[c] = s1 / fmaxf(cnt1[g], 1.0f);
    cat[c + D] = s2 / fmaxf(cnt2[g], 1.0f);
    __syncthreads();
    float acc = lin1b[c];
#pragma unroll 8
    for (int k = 0; k < 2 * D; k++) acc += cat[k] * lin1W[k * D + c];
    acc = fmaxf(acc, 0.0f);
    float v = acc * lin2W[c];
#pragma unroll
    for (int off = 32; off > 0; off >>= 1) v += __shfl_down(v, off, 64);
    __shared__ float wsum[2];
    if ((c & 63) == 0) wsum[c >> 6] = v;
    __syncthreads();
    if (c == 0) out[g] = wsum[0] + wsum[1] + lin2b[0];
}

extern "C" void kernel_launch(void* const* d_in, const int* in_sizes, int n_in,
                              void* d_out, int out_size, void* d_ws, size_t ws_size,
                              hipStream_t stream) {
    const float* xs[2]      = {(const float*)d_in[0], (const float*)d_in[3]};
    const int*   eis[2]     = {(const int*)d_in[1], (const int*)d_in[4]};
    const int*   batches[2] = {(const int*)d_in[2], (const int*)d_in[5]};
    const float* W0[2] = {(const float*)d_in[6],  (const float*)d_in[10]};
    const float* b0[2] = {(const float*)d_in[7],  (const float*)d_in[11]};
    const float* W1[2] = {(const float*)d_in[8],  (const float*)d_in[12]};
    const float* b1[2] = {(const float*)d_in[9],  (const float*)d_in[13]};
    const float* lin1W = (const float*)d_in[14];
    const float* lin1b = (const float*)d_in[15];
    const float* lin2W = (const float*)d_in[16];
    const float* lin2b = (const float*)d_in[17];
    float* out = (float*)d_out;

    __half* WtH = (__half*)d_ws;                          // 65536 halves (128 KB)
    __half* ACT = WtH + 65536;                            // N*D halves
    __half* H   = ACT + (size_t)N_NODES * D;              // N*D halves
    int*    cnti = (int*)(H + (size_t)N_NODES * D);       // NPAD ints
    int*    gcnt0 = cnti + NPAD;                          // 196
    int*    gcnt1 = gcnt0 + BUCKETS;                      // 196
    int*    ocnt0 = gcnt1 + BUCKETS;                      // 1
    int*    ocnt1 = ocnt0 + 1;                            // 1 (+6 pad)
    int2*   ovf  = (int2*)(gcnt0 + 400);                  // OVF_CAP pairs
    unsigned short* ell = (unsigned short*)(ovf + OVF_CAP);   // NPAD*ELLW ushorts
    int2*   bucketed = (int2*)(ell + (size_t)NPAD * ELLW);    // BUCKETS*BCAP pairs (8 MB)
    float*  pp1  = (float*)(bucketed + (size_t)BUCKETS * BCAP);
    float*  pp2  = pp1 + (size_t)N_GRAPHS * POOL_PARTS * D;
    float*  cnt1 = pp2 + (size_t)N_GRAPHS * POOL_PARTS * D;
    float*  cnt2 = cnt1 + N_GRAPHS;
    int*    gcnts[2] = {gcnt0, gcnt1};
    int*    ocnts[2] = {ocnt0, ocnt1};
    float*  pps[2]   = {pp1, pp2};
    float*  cnts[2]  = {cnt1, cnt2};

    dim3 b256(256);
    int partBlocks = (N_EDGES + EPB - 1) / EPB;  // 196
    int gemmBlocks = (N_NODES + 63) / 64;        // 782
    int aggBlocks  = N_NODES / 4;                // 12500

    k_prep<<<4, b256, 0, stream>>>(W0[0], W1[0], W0[1], W1[1], WtH);
    hipMemsetAsync(gcnt0, 0, 400 * sizeof(int), stream);  // gcnt0, gcnt1, ocnt0, ocnt1

    for (int br = 0; br < 2; br++) {
        const int* srcp = eis[br];
        const int* dstp = eis[br] + N_EDGES;

        k_part<<<partBlocks, b256, 0, stream>>>(srcp, dstp, gcnts[br], bucketed);
        k_build<<<BUCKETS, b256, 0, stream>>>(gcnts[br], bucketed, cnti, ell, ovf, ocnts[br]);

        k_gemm<false><<<gemmBlocks, b256, 0, stream>>>(xs[br], WtH + (size_t)(br * 2 + 0) * 16384, cnti, H);
        k_agg<<<aggBlocks, b256, 0, stream>>>(cnti, ell, ovf, ocnts[br], H, b0[br], ACT);
        k_gemm<true><<<gemmBlocks, b256, 0, stream>>>(ACT, WtH + (size_t)(br * 2 + 1) * 16384, cnti, H);
        k_agg<<<aggBlocks, b256, 0, stream>>>(cnti, ell, ovf, ocnts[br], H, b1[br], ACT);

        k_pool<<<dim3(N_GRAPHS, POOL_PARTS), b256, 0, stream>>>(ACT, batches[br], pps[br], cnts[br]);
    }
    k_mlp<<<N_GRAPHS, dim3(128), 0, stream>>>(pp1, pp2, cnt1, cnt2, lin1W, lin1b, lin2W, lin2b, out);
}

// Round 13
// 456.370 us; speedup vs baseline: 1.2545x; 1.0394x over previous
//
#include <hip/hip_runtime.h>
#include <hip/hip_fp16.h>

#define N_NODES 50000
#define N_EDGES 800000
#define D 128
#define N_GRAPHS 64
#define NEG_SLOPE 0.01f
#define POOL_PARTS 8
#define ELLW 32      // 32 ushort slots = 64 B per node row
#define OVF_CAP 8192 // overflow pairs; expected usage ~30

#define BUCKETS 196  // dst>>8 -> 196 buckets of 256 nodes
#define NPAD (BUCKETS * 256)
#define EPB 4096     // edges per phase-A block
#define BCAP 5120    // per-bucket capacity

typedef _Float16 half8 __attribute__((ext_vector_type(8)));
typedef _Float16 half4 __attribute__((ext_vector_type(4)));
typedef float f32x4 __attribute__((ext_vector_type(4)));
typedef float f32x2 __attribute__((ext_vector_type(2)));

// ---------------- W transpose+cast prep: WtH[w][n*128+k] = (half)W[k*128+n] ----------------
__global__ __launch_bounds__(256) void k_prep(const float* __restrict__ Wa, const float* __restrict__ Wb,
                                              const float* __restrict__ Wc, const float* __restrict__ Wd,
                                              __half* __restrict__ WtH) {
    const float* Ws[4] = {Wa, Wb, Wc, Wd};
    const float* W = Ws[blockIdx.x];
    __half* o = WtH + (size_t)blockIdx.x * 16384;
    int t = threadIdx.x;
    for (int r = 0; r < 64; r++) {
        int e = r * 256 + t;
        int k = e >> 7, n = e & 127;
        o[n * 128 + k] = __float2half(W[k * 128 + n]);
    }
}

// ---------------- Phase A: partition edges into dst-buckets (coalesced writes) ----------------
__global__ __launch_bounds__(256) void k_part(const int* __restrict__ src, const int* __restrict__ dst,
                                              int* __restrict__ gcnt, int2* __restrict__ bucketed) {
    __shared__ int bcnt[BUCKETS];
    __shared__ int bofs[BUCKETS];
    __shared__ int gbase[BUCKETS];
    __shared__ int2 stage[EPB];
    const int tid = threadIdx.x;
    const int base = blockIdx.x * EPB;
    for (int b = tid; b < BUCKETS; b += 256) bcnt[b] = 0;
    __syncthreads();
    int d_[16], s_[16], p_[16];
#pragma unroll
    for (int k = 0; k < 16; k++) {
        int i = base + k * 256 + tid;
        bool v = i < N_EDGES;
        d_[k] = v ? dst[i] : -1;
        s_[k] = v ? src[i] : 0;
        p_[k] = 0;
        if (v) p_[k] = atomicAdd(&bcnt[d_[k] >> 8], 1);
    }
    __syncthreads();
    if (tid == 0) {
        int run = 0;
        for (int b = 0; b < BUCKETS; b++) { bofs[b] = run; run += bcnt[b]; }
    }
    __syncthreads();
    if (tid < BUCKETS) gbase[tid] = atomicAdd(&gcnt[tid], bcnt[tid]);
    __syncthreads();
#pragma unroll
    for (int k = 0; k < 16; k++) {
        if (d_[k] >= 0) stage[bofs[d_[k] >> 8] + p_[k]] = make_int2(d_[k], s_[k]);
    }
    __syncthreads();
    int total = bofs[BUCKETS - 1] + bcnt[BUCKETS - 1];
    for (int i = tid; i < total; i += 256) {
        int2 e = stage[i];
        int b = e.x >> 8;
        int dest = gbase[b] + (i - bofs[b]);
        if (dest < BCAP) bucketed[(size_t)b * BCAP + dest] = e;
    }
}

// ---------------- Phase B: build ELL tile per bucket in LDS, write coalesced ----------------
__global__ __launch_bounds__(256) void k_build(const int* __restrict__ gcnt, const int2* __restrict__ bucketed,
                                               int* __restrict__ cnti, unsigned short* __restrict__ ell,
                                               int2* __restrict__ ovf, int* __restrict__ ocnt) {
    __shared__ unsigned short lell[256 * ELLW];
    __shared__ int lcnt[256];
    const int b = blockIdx.x, tid = threadIdx.x;
    lcnt[tid] = 0;
    __syncthreads();
    int nb = min(gcnt[b], BCAP);
    const int2* __restrict__ bp = bucketed + (size_t)b * BCAP;
    for (int i = tid; i < nb; i += 256) {
        int2 e = bp[i];
        int dl = e.x & 255;
        int p = atomicAdd(&lcnt[dl], 1);
        if (p < ELLW) {
            lell[dl * ELLW + p] = (unsigned short)e.y;
        } else {
            int o = atomicAdd(ocnt, 1);
            if (o < OVF_CAP) ovf[o] = e;
        }
    }
    __syncthreads();
    cnti[b * 256 + tid] = lcnt[tid];
    uint4* eg = (uint4*)(ell + (size_t)b * 256 * ELLW);
    const uint4* el = (const uint4*)lell;
    for (int i = tid; i < 256 * ELLW * 2 / 16; i += 256) eg[i] = el[i];
}

// ---------------- MFMA GEMM: H[N,128](fp8 e4m3) = (x @ W) * rsqrt(cnt+1) ----------------
#define XS 136
template <bool FP16IN>
__global__ __launch_bounds__(256) void k_gemm(const void* __restrict__ xin, const __half* __restrict__ WtH,
                                              const int* __restrict__ cnt, unsigned char* __restrict__ h) {
    __shared__ _Float16 Xl[64 * XS];
    __shared__ _Float16 Wt[128 * XS];
    const int tid = threadIdx.x;
    const int w = tid >> 6, lane = tid & 63;
    const int quad = lane >> 4, l16 = lane & 15;
    const int row0 = blockIdx.x * 64;

#pragma unroll
    for (int i = 0; i < 8; i++) {
        int i2 = tid + 256 * i;
        int r = i2 >> 4, cg = i2 & 15;
        *(uint4*)&Wt[r * XS + cg * 8] = ((const uint4*)WtH)[i2];
    }
    if (FP16IN) {
        const __half* x = (const __half*)xin;
#pragma unroll
        for (int i = 0; i < 4; i++) {
            int i2 = tid + 256 * i;
            int r = i2 >> 4, cg = i2 & 15;
            uint4 v = make_uint4(0, 0, 0, 0);
            if (row0 + r < N_NODES) v = ((const uint4*)(x + (size_t)(row0 + r) * D))[cg];
            *(uint4*)&Xl[r * XS + cg * 8] = v;
        }
    } else {
        const float* x = (const float*)xin;
#pragma unroll
        for (int i = 0; i < 8; i++) {
            int i2 = tid + 256 * i;
            int r = i2 >> 5, f4 = i2 & 31;
            float4 v = make_float4(0.f, 0.f, 0.f, 0.f);
            if (row0 + r < N_NODES) v = *(const float4*)((const float*)x + (size_t)(row0 + r) * D + f4 * 4);
            half4 hv;
            hv[0] = (_Float16)v.x; hv[1] = (_Float16)v.y; hv[2] = (_Float16)v.z; hv[3] = (_Float16)v.w;
            *(half4*)&Xl[r * XS + f4 * 4] = hv;
        }
    }
    __syncthreads();

    half8 a[4];
#pragma unroll
    for (int kb = 0; kb < 4; kb++)
        a[kb] = *(const half8*)&Xl[(w * 16 + l16) * XS + kb * 32 + quad * 8];

    const int rbase = row0 + w * 16 + quad * 4;
    float di[4];
#pragma unroll
    for (int reg = 0; reg < 4; reg++) {
        int r = rbase + reg;
        di[reg] = (r < N_NODES) ? rsqrtf((float)cnt[r] + 1.0f) : 0.0f;
    }

    float accs[8][4];
#pragma unroll
    for (int ct = 0; ct < 8; ct++) {
        f32x4 acc = {0.f, 0.f, 0.f, 0.f};
#pragma unroll
        for (int kb = 0; kb < 4; kb++) {
            half8 b = *(const half8*)&Wt[(ct * 16 + l16) * XS + kb * 32 + quad * 8];
            acc = __builtin_amdgcn_mfma_f32_16x16x32_f16(a[kb], b, acc, 0, 0, 0);
        }
#pragma unroll
        for (int reg = 0; reg < 4; reg++) accs[ct][reg] = acc[reg] * di[reg];
    }

    // fp8 epilogue: stage 64x128 bytes in LDS (reuse Xl), then coalesced 16B stores
    __syncthreads();  // all waves done with Xl (a-frags loaded)
    unsigned char* S = (unsigned char*)Xl;
#pragma unroll
    for (int ct = 0; ct < 8; ct++)
#pragma unroll
        for (int reg = 0; reg < 4; reg++) {
            int p = __builtin_amdgcn_cvt_pk_fp8_f32(accs[ct][reg], accs[ct][reg], 0, false);
            S[(w * 16 + quad * 4 + reg) * 128 + ct * 16 + l16] = (unsigned char)p;
        }
    __syncthreads();
#pragma unroll
    for (int i = 0; i < 2; i++) {
        int idx = tid + 256 * i;          // 512 uint4 = 64 rows x 8
        int r = idx >> 3, cg = idx & 7;
        if (row0 + r < N_NODES)
            ((uint4*)(h + (size_t)(row0 + r) * 128))[cg] = ((const uint4*)S)[idx];
    }
}

// ---------------- ELL aggregation: one wave per dst node, fp8 gathers ----------------
// out(fp16)[d] = leaky( dinv[d] * (H[d] + sum H[src]) + bias )
__global__ __launch_bounds__(256) void k_agg(const int* __restrict__ cnt, const unsigned short* __restrict__ ell,
                                             const int2* __restrict__ ovf, const int* __restrict__ ocnt,
                                             const unsigned char* __restrict__ H8, const float* __restrict__ bias,
                                             __half* __restrict__ out) {
    int lane = threadIdx.x & 63;
    int node = __builtin_amdgcn_readfirstlane(blockIdx.x * 4 + (threadIdx.x >> 6));
    int n = cnt[node];
    int nc = min(n, ELLW);
    const unsigned short* __restrict__ ep = ell + (size_t)node * ELLW;
    float2 acc[8];
    {
        unsigned short hv16 = *(const unsigned short*)(H8 + (size_t)node * 128 + lane * 2);
        f32x2 v = __builtin_amdgcn_cvt_pk_f32_fp8((int)hv16, false);
        acc[0] = make_float2(v[0], v[1]);  // self term (already dinv-scaled)
    }
#pragma unroll
    for (int i = 1; i < 8; i++) acc[i] = make_float2(0.f, 0.f);
    for (int j = 0; j < nc; j += 8) {
        int s[8]; float w[8];
#pragma unroll
        for (int i = 0; i < 8; i++) {
            bool v = (j + i) < nc;
            s[i] = v ? (int)ep[j + i] : 0;
            w[i] = v ? 1.0f : 0.0f;
        }
#pragma unroll
        for (int i = 0; i < 8; i++) {
            unsigned short hv16 = *(const unsigned short*)(H8 + (size_t)s[i] * 128 + lane * 2);
            f32x2 hv = __builtin_amdgcn_cvt_pk_f32_fp8((int)hv16, false);
            acc[i].x = fmaf(w[i], hv[0], acc[i].x);
            acc[i].y = fmaf(w[i], hv[1], acc[i].y);
        }
    }
    if (n > ELLW) {
        int oc = min(*ocnt, OVF_CAP);
        for (int o = 0; o < oc; o++) {
            int2 p = ovf[o];
            if (p.x == node) {
                unsigned short hv16 = *(const unsigned short*)(H8 + (size_t)p.y * 128 + lane * 2);
                f32x2 hv = __builtin_amdgcn_cvt_pk_f32_fp8((int)hv16, false);
                acc[0].x += hv[0]; acc[0].y += hv[1];
            }
        }
    }
    float sx = ((acc[0].x + acc[1].x) + (acc[2].x + acc[3].x)) + ((acc[4].x + acc[5].x) + (acc[6].x + acc[7].x));
    float sy = ((acc[0].y + acc[1].y) + (acc[2].y + acc[3].y)) + ((acc[4].y + acc[5].y) + (acc[6].y + acc[7].y));
    float dv = rsqrtf((float)n + 1.0f);
    float2 b = ((const float2*)bias)[lane];
    float vx = sx * dv + b.x;
    float vy = sy * dv + b.y;
    vx = vx > 0.0f ? vx : NEG_SLOPE * vx;
    vy = vy > 0.0f ? vy : NEG_SLOPE * vy;
    ((__half2*)out)[(size_t)node * 64 + lane] = __floats2half2_rn(vx, vy);
}

// ---------------- mean pool (fp16 in): per-(graph,part) float partials ----------------
__device__ __forceinline__ int lower_bound_i(const int* __restrict__ arr, int n, int key) {
    int lo = 0, hi = n;
    while (lo < hi) {
        int mid = (lo + hi) >> 1;
        if (arr[mid] < key) lo = mid + 1; else hi = mid;
    }
    return lo;
}

__global__ __launch_bounds__(256) void k_pool(const __half* __restrict__ h, const int* __restrict__ batch,
                                              float* __restrict__ pp, float* __restrict__ cnt) {
    int g = blockIdx.x;
    int part = blockIdx.y;
    int lo = lower_bound_i(batch, N_NODES, g);
    int hi = lower_bound_i(batch, N_NODES, g + 1);
    int num = hi - lo;
    if (part == 0 && threadIdx.x == 0) cnt[g] = (float)num;
    int chunk = (num + POOL_PARTS - 1) / POOL_PARTS;
    int a = lo + part * chunk;
    int b = min(a + chunk, hi);
    int c2 = threadIdx.x & 63;
    int sub = threadIdx.x >> 6;
    const __half2* __restrict__ h2 = (const __half2*)h;
    float2 acc = make_float2(0.f, 0.f);
    for (int node = a + sub; node < b; node += 4) {
        float2 v = __half22float2(h2[(size_t)node * 64 + c2]);
        acc.x += v.x; acc.y += v.y;
    }
    __shared__ float2 tmp[256];
    tmp[threadIdx.x] = acc;
    __syncthreads();
    if (sub == 0) {
        float2 s;
        s.x = tmp[c2].x + tmp[c2 + 64].x + tmp[c2 + 128].x + tmp[c2 + 192].x;
        s.y = tmp[c2].y + tmp[c2 + 64].y + tmp[c2 + 128].y + tmp[c2 + 192].y;
        ((float2*)pp)[((size_t)g * POOL_PARTS + part) * 64 + c2] = s;
    }
}

// ---------------- final MLP (reduces pool parts) ----------------
__global__ __launch_bounds__(128) void k_mlp(const float* __restrict__ pp1, const float* __restrict__ pp2,
                                             const float* __restrict__ cnt1, const float* __restrict__ cnt2,
                                             const float* __restrict__ lin1W, const float* __restrict__ lin1b,
                                             const float* __restrict__ lin2W, const float* __restrict__ lin2b,
                                             float* __restrict__ out) {
    int g = blockIdx.x;
    int c = threadIdx.x;
    __shared__ float cat[2 * D];
    float s1 = 0.f, s2 = 0.f;
#pragma unroll
    for (int p = 0; p < POOL_PARTS; p++) {
        s1 += pp1[((size_t)g * POOL_PARTS + p) * D + c];
        s2 += pp2[((size_t)g * POOL_PARTS + p) * D + c];
    }
    cat[c] = s1 / fmaxf(cnt1[g], 1.0f);
    cat[c + D] = s2 / fmaxf(cnt2[g], 1.0f);
    __syncthreads();
    float acc = lin1b[c];
#pragma unroll 8
    for (int k = 0; k < 2 * D; k++) acc += cat[k] * lin1W[k * D + c];
    acc = fmaxf(acc, 0.0f);
    float v = acc * lin2W[c];
#pragma unroll
    for (int off = 32; off > 0; off >>= 1) v += __shfl_down(v, off, 64);
    __shared__ float wsum[2];
    if ((c & 63) == 0) wsum[c >> 6] = v;
    __syncthreads();
    if (c == 0) out[g] = wsum[0] + wsum[1] + lin2b[0];
}

extern "C" void kernel_launch(void* const* d_in, const int* in_sizes, int n_in,
                              void* d_out, int out_size, void* d_ws, size_t ws_size,
                              hipStream_t stream) {
    const float* xs[2]      = {(const float*)d_in[0], (const float*)d_in[3]};
    const int*   eis[2]     = {(const int*)d_in[1], (const int*)d_in[4]};
    const int*   batches[2] = {(const int*)d_in[2], (const int*)d_in[5]};
    const float* W0[2] = {(const float*)d_in[6],  (const float*)d_in[10]};
    const float* b0[2] = {(const float*)d_in[7],  (const float*)d_in[11]};
    const float* W1[2] = {(const float*)d_in[8],  (const float*)d_in[12]};
    const float* b1[2] = {(const float*)d_in[9],  (const float*)d_in[13]};
    const float* lin1W = (const float*)d_in[14];
    const float* lin1b = (const float*)d_in[15];
    const float* lin2W = (const float*)d_in[16];
    const float* lin2b = (const float*)d_in[17];
    float* out = (float*)d_out;

    __half* WtH = (__half*)d_ws;                          // 65536 halves (128 KB)
    __half* ACT = WtH + 65536;                            // N*D halves
    unsigned char* H8 = (unsigned char*)(ACT + (size_t)N_NODES * D);  // N*128 bytes
    int*    cnti = (int*)(H8 + (size_t)N_NODES * 128);    // NPAD ints
    int*    gcnt0 = cnti + NPAD;                          // 196
    int*    gcnt1 = gcnt0 + BUCKETS;                      // 196
    int*    ocnt0 = gcnt1 + BUCKETS;                      // 1
    int*    ocnt1 = ocnt0 + 1;                            // 1 (+pad)
    int2*   ovf  = (int2*)(gcnt0 + 400);                  // OVF_CAP pairs
    unsigned short* ell = (unsigned short*)(ovf + OVF_CAP);   // NPAD*ELLW ushorts
    int2*   bucketed = (int2*)(ell + (size_t)NPAD * ELLW);    // BUCKETS*BCAP pairs
    float*  pp1  = (float*)(bucketed + (size_t)BUCKETS * BCAP);
    float*  pp2  = pp1 + (size_t)N_GRAPHS * POOL_PARTS * D;
    float*  cnt1 = pp2 + (size_t)N_GRAPHS * POOL_PARTS * D;
    float*  cnt2 = cnt1 + N_GRAPHS;
    int*    gcnts[2] = {gcnt0, gcnt1};
    int*    ocnts[2] = {ocnt0, ocnt1};
    float*  pps[2]   = {pp1, pp2};
    float*  cnts[2]  = {cnt1, cnt2};

    dim3 b256(256);
    int partBlocks = (N_EDGES + EPB - 1) / EPB;  // 196
    int gemmBlocks = (N_NODES + 63) / 64;        // 782
    int aggBlocks  = N_NODES / 4;                // 12500

    k_prep<<<4, b256, 0, stream>>>(W0[0], W1[0], W0[1], W1[1], WtH);
    hipMemsetAsync(gcnt0, 0, 400 * sizeof(int), stream);

    for (int br = 0; br < 2; br++) {
        const int* srcp = eis[br];
        const int* dstp = eis[br] + N_EDGES;

        k_part<<<partBlocks, b256, 0, stream>>>(srcp, dstp, gcnts[br], bucketed);
        k_build<<<BUCKETS, b256, 0, stream>>>(gcnts[br], bucketed, cnti, ell, ovf, ocnts[br]);

        k_gemm<false><<<gemmBlocks, b256, 0, stream>>>(xs[br], WtH + (size_t)(br * 2 + 0) * 16384, cnti, H8);
        k_agg<<<aggBlocks, b256, 0, stream>>>(cnti, ell, ovf, ocnts[br], H8, b0[br], ACT);
        k_gemm<true><<<gemmBlocks, b256, 0, stream>>>(ACT, WtH + (size_t)(br * 2 + 1) * 16384, cnti, H8);
        k_agg<<<aggBlocks, b256, 0, stream>>>(cnti, ell, ovf, ocnts[br], H8, b1[br], ACT);

        k_pool<<<dim3(N_GRAPHS, POOL_PARTS), b256, 0, stream>>>(ACT, batches[br], pps[br], cnts[br]);
    }
    k_mlp<<<N_GRAPHS, dim3(128), 0, stream>>>(pp1, pp2, cnt1, cnt2, lin1W, lin1b, lin2W, lin2b, out);
}

// Round 14
// 355.072 us; speedup vs baseline: 1.6124x; 1.2853x over previous
//
#include <hip/hip_runtime.h>
#include <hip/hip_fp16.h>

#define N_NODES 50000
#define N_EDGES 800000
#define D 128
#define N_GRAPHS 64
#define NEG_SLOPE 0.01f
#define POOL_PARTS 8
#define ELLW 32      // 32 ushort slots = 64 B per node row
#define OVF_CAP 8192 // overflow pairs; expected usage ~30

#define BUCKETS 196  // dst>>8 -> 196 buckets of 256 nodes
#define NPAD (BUCKETS * 256)
#define EPB 4096     // edges per phase-A block
#define BCAP 5120    // per-bucket capacity

typedef _Float16 half8 __attribute__((ext_vector_type(8)));
typedef _Float16 half4 __attribute__((ext_vector_type(4)));
typedef float f32x4 __attribute__((ext_vector_type(4)));
typedef float f32x2 __attribute__((ext_vector_type(2)));

// ---------------- W transpose+cast prep: WtH[w][n*128+k] = (half)W[k*128+n] ----------------
__global__ __launch_bounds__(256) void k_prep(const float* __restrict__ Wa, const float* __restrict__ Wb,
                                              const float* __restrict__ Wc, const float* __restrict__ Wd,
                                              __half* __restrict__ WtH) {
    const float* Ws[4] = {Wa, Wb, Wc, Wd};
    const float* W = Ws[blockIdx.x];
    __half* o = WtH + (size_t)blockIdx.x * 16384;
    int t = threadIdx.x;
    for (int r = 0; r < 64; r++) {
        int e = r * 256 + t;
        int k = e >> 7, n = e & 127;
        o[n * 128 + k] = __float2half(W[k * 128 + n]);
    }
}

// ---------------- Phase A: partition edges into dst-buckets (coalesced writes) ----------------
__global__ __launch_bounds__(256) void k_part(const int* __restrict__ src, const int* __restrict__ dst,
                                              int* __restrict__ gcnt, int2* __restrict__ bucketed) {
    __shared__ int bcnt[BUCKETS];
    __shared__ int bofs[BUCKETS];
    __shared__ int gbase[BUCKETS];
    __shared__ int2 stage[EPB];
    const int tid = threadIdx.x;
    const int base = blockIdx.x * EPB;
    for (int b = tid; b < BUCKETS; b += 256) bcnt[b] = 0;
    __syncthreads();
    int d_[16], s_[16], p_[16];
#pragma unroll
    for (int k = 0; k < 16; k++) {
        int i = base + k * 256 + tid;
        bool v = i < N_EDGES;
        d_[k] = v ? dst[i] : -1;
        s_[k] = v ? src[i] : 0;
        p_[k] = 0;
        if (v) p_[k] = atomicAdd(&bcnt[d_[k] >> 8], 1);
    }
    __syncthreads();
    if (tid == 0) {
        int run = 0;
        for (int b = 0; b < BUCKETS; b++) { bofs[b] = run; run += bcnt[b]; }
    }
    __syncthreads();
    if (tid < BUCKETS) gbase[tid] = atomicAdd(&gcnt[tid], bcnt[tid]);
    __syncthreads();
#pragma unroll
    for (int k = 0; k < 16; k++) {
        if (d_[k] >= 0) stage[bofs[d_[k] >> 8] + p_[k]] = make_int2(d_[k], s_[k]);
    }
    __syncthreads();
    int total = bofs[BUCKETS - 1] + bcnt[BUCKETS - 1];
    for (int i = tid; i < total; i += 256) {
        int2 e = stage[i];
        int b = e.x >> 8;
        int dest = gbase[b] + (i - bofs[b]);
        if (dest < BCAP) bucketed[(size_t)b * BCAP + dest] = e;
    }
}

// ---------------- Phase B: build ELL tile per bucket in LDS, write coalesced ----------------
__global__ __launch_bounds__(256) void k_build(const int* __restrict__ gcnt, const int2* __restrict__ bucketed,
                                               int* __restrict__ cnti, unsigned short* __restrict__ ell,
                                               int2* __restrict__ ovf, int* __restrict__ ocnt) {
    __shared__ unsigned short lell[256 * ELLW];
    __shared__ int lcnt[256];
    const int b = blockIdx.x, tid = threadIdx.x;
    lcnt[tid] = 0;
    __syncthreads();
    int nb = min(gcnt[b], BCAP);
    const int2* __restrict__ bp = bucketed + (size_t)b * BCAP;
    for (int i = tid; i < nb; i += 256) {
        int2 e = bp[i];
        int dl = e.x & 255;
        int p = atomicAdd(&lcnt[dl], 1);
        if (p < ELLW) {
            lell[dl * ELLW + p] = (unsigned short)e.y;
        } else {
            int o = atomicAdd(ocnt, 1);
            if (o < OVF_CAP) ovf[o] = e;
        }
    }
    __syncthreads();
    cnti[b * 256 + tid] = lcnt[tid];
    uint4* eg = (uint4*)(ell + (size_t)b * 256 * ELLW);
    const uint4* el = (const uint4*)lell;
    for (int i = tid; i < 256 * ELLW * 2 / 16; i += 256) eg[i] = el[i];
}

// ---------------- MFMA GEMM: H[N,128](fp8 e4m3) = (x @ W) * rsqrt(cnt+1) ----------------
#define XS 136
template <bool FP16IN>
__global__ __launch_bounds__(256) void k_gemm(const void* __restrict__ xin, const __half* __restrict__ WtH,
                                              const int* __restrict__ cnt, unsigned char* __restrict__ h) {
    __shared__ _Float16 Xl[64 * XS];
    __shared__ _Float16 Wt[128 * XS];
    const int tid = threadIdx.x;
    const int w = tid >> 6, lane = tid & 63;
    const int quad = lane >> 4, l16 = lane & 15;
    const int row0 = blockIdx.x * 64;

#pragma unroll
    for (int i = 0; i < 8; i++) {
        int i2 = tid + 256 * i;
        int r = i2 >> 4, cg = i2 & 15;
        *(uint4*)&Wt[r * XS + cg * 8] = ((const uint4*)WtH)[i2];
    }
    if (FP16IN) {
        const __half* x = (const __half*)xin;
#pragma unroll
        for (int i = 0; i < 4; i++) {
            int i2 = tid + 256 * i;
            int r = i2 >> 4, cg = i2 & 15;
            uint4 v = make_uint4(0, 0, 0, 0);
            if (row0 + r < N_NODES) v = ((const uint4*)(x + (size_t)(row0 + r) * D))[cg];
            *(uint4*)&Xl[r * XS + cg * 8] = v;
        }
    } else {
        const float* x = (const float*)xin;
#pragma unroll
        for (int i = 0; i < 8; i++) {
            int i2 = tid + 256 * i;
            int r = i2 >> 5, f4 = i2 & 31;
            float4 v = make_float4(0.f, 0.f, 0.f, 0.f);
            if (row0 + r < N_NODES) v = *(const float4*)((const float*)x + (size_t)(row0 + r) * D + f4 * 4);
            half4 hv;
            hv[0] = (_Float16)v.x; hv[1] = (_Float16)v.y; hv[2] = (_Float16)v.z; hv[3] = (_Float16)v.w;
            *(half4*)&Xl[r * XS + f4 * 4] = hv;
        }
    }
    __syncthreads();

    half8 a[4];
#pragma unroll
    for (int kb = 0; kb < 4; kb++)
        a[kb] = *(const half8*)&Xl[(w * 16 + l16) * XS + kb * 32 + quad * 8];

    const int rbase = row0 + w * 16 + quad * 4;
    float di[4];
#pragma unroll
    for (int reg = 0; reg < 4; reg++) {
        int r = rbase + reg;
        di[reg] = (r < N_NODES) ? rsqrtf((float)cnt[r] + 1.0f) : 0.0f;
    }

    float accs[8][4];
#pragma unroll
    for (int ct = 0; ct < 8; ct++) {
        f32x4 acc = {0.f, 0.f, 0.f, 0.f};
#pragma unroll
        for (int kb = 0; kb < 4; kb++) {
            half8 b = *(const half8*)&Wt[(ct * 16 + l16) * XS + kb * 32 + quad * 8];
            acc = __builtin_amdgcn_mfma_f32_16x16x32_f16(a[kb], b, acc, 0, 0, 0);
        }
#pragma unroll
        for (int reg = 0; reg < 4; reg++) accs[ct][reg] = acc[reg] * di[reg];
    }

    // fp8 epilogue: stage 64x128 bytes in LDS (reuse Xl), then coalesced 16B stores
    __syncthreads();
    unsigned char* S = (unsigned char*)Xl;
#pragma unroll
    for (int ct = 0; ct < 8; ct++)
#pragma unroll
        for (int reg = 0; reg < 4; reg++) {
            int p = __builtin_amdgcn_cvt_pk_fp8_f32(accs[ct][reg], accs[ct][reg], 0, false);
            S[(w * 16 + quad * 4 + reg) * 128 + ct * 16 + l16] = (unsigned char)p;
        }
    __syncthreads();
#pragma unroll
    for (int i = 0; i < 2; i++) {
        int idx = tid + 256 * i;
        int r = idx >> 3, cg = idx & 7;
        if (row0 + r < N_NODES)
            ((uint4*)(h + (size_t)(row0 + r) * 128))[cg] = ((const uint4*)S)[idx];
    }
}

// ---------------- ELL aggregation: 2 nodes/wave, 32 lanes/node, 4B fp8 gathers ----------------
// out(fp16)[d] = leaky( dinv[d] * (H[d] + sum H[src]) + bias )
__global__ __launch_bounds__(256) void k_agg(const int* __restrict__ cnt, const unsigned short* __restrict__ ell,
                                             const int2* __restrict__ ovf, const int* __restrict__ ocnt,
                                             const unsigned char* __restrict__ H8, const float* __restrict__ bias,
                                             __half* __restrict__ out) {
    const int tid = threadIdx.x;
    const int l32 = tid & 31;                 // lane within half-wave
    const int node = blockIdx.x * 8 + (tid >> 5);  // 8 halves per block
    int n = cnt[node];
    int nc = min(n, ELLW);
    // preload this half's edge list: lane l32 holds slot l32 (0 if beyond count)
    int sv = 0;
    if (l32 < nc) sv = (int)ell[(size_t)node * ELLW + l32];
    // wave-uniform loop bound = max(ncA, ncB)
    int ncOther = __shfl(nc, (tid & 63) ^ 32, 64);
    int jmax = max(nc, ncOther);

    float4 acc[8];
    {
        unsigned int dw = *(const unsigned int*)(H8 + (size_t)node * 128 + l32 * 4);
        f32x2 lo = __builtin_amdgcn_cvt_pk_f32_fp8((int)dw, false);
        f32x2 hi = __builtin_amdgcn_cvt_pk_f32_fp8((int)dw, true);
        acc[0] = make_float4(lo[0], lo[1], hi[0], hi[1]);  // self term (already dinv-scaled)
    }
#pragma unroll
    for (int i = 1; i < 8; i++) acc[i] = make_float4(0.f, 0.f, 0.f, 0.f);

    for (int j = 0; j < jmax; j += 8) {
        int s[8]; float w[8];
#pragma unroll
        for (int i = 0; i < 8; i++) {
            s[i] = __shfl(sv, j + i, 32);      // broadcast within this half; 0 if slot empty
            w[i] = ((j + i) < nc) ? 1.0f : 0.0f;
        }
#pragma unroll
        for (int i = 0; i < 8; i++) {
            unsigned int dw = *(const unsigned int*)(H8 + (size_t)s[i] * 128 + l32 * 4);
            f32x2 lo = __builtin_amdgcn_cvt_pk_f32_fp8((int)dw, false);
            f32x2 hi = __builtin_amdgcn_cvt_pk_f32_fp8((int)dw, true);
            acc[i].x = fmaf(w[i], lo[0], acc[i].x);
            acc[i].y = fmaf(w[i], lo[1], acc[i].y);
            acc[i].z = fmaf(w[i], hi[0], acc[i].z);
            acc[i].w = fmaf(w[i], hi[1], acc[i].w);
        }
    }
    if (n > ELLW) {  // rare overflow path
        int oc = min(*ocnt, OVF_CAP);
        for (int o = 0; o < oc; o++) {
            int2 p = ovf[o];
            if (p.x == node) {
                unsigned int dw = *(const unsigned int*)(H8 + (size_t)p.y * 128 + l32 * 4);
                f32x2 lo = __builtin_amdgcn_cvt_pk_f32_fp8((int)dw, false);
                f32x2 hi = __builtin_amdgcn_cvt_pk_f32_fp8((int)dw, true);
                acc[0].x += lo[0]; acc[0].y += lo[1]; acc[0].z += hi[0]; acc[0].w += hi[1];
            }
        }
    }
    float sx = ((acc[0].x + acc[1].x) + (acc[2].x + acc[3].x)) + ((acc[4].x + acc[5].x) + (acc[6].x + acc[7].x));
    float sy = ((acc[0].y + acc[1].y) + (acc[2].y + acc[3].y)) + ((acc[4].y + acc[5].y) + (acc[6].y + acc[7].y));
    float sz = ((acc[0].z + acc[1].z) + (acc[2].z + acc[3].z)) + ((acc[4].z + acc[5].z) + (acc[6].z + acc[7].z));
    float sw = ((acc[0].w + acc[1].w) + (acc[2].w + acc[3].w)) + ((acc[4].w + acc[5].w) + (acc[6].w + acc[7].w));
    float dv = rsqrtf((float)n + 1.0f);
    float4 b = ((const float4*)bias)[l32];
    float vx = sx * dv + b.x;
    float vy = sy * dv + b.y;
    float vz = sz * dv + b.z;
    float vw = sw * dv + b.w;
    vx = vx > 0.0f ? vx : NEG_SLOPE * vx;
    vy = vy > 0.0f ? vy : NEG_SLOPE * vy;
    vz = vz > 0.0f ? vz : NEG_SLOPE * vz;
    vw = vw > 0.0f ? vw : NEG_SLOPE * vw;
    union { __half2 h2[2]; uint2 u; } up;
    up.h2[0] = __floats2half2_rn(vx, vy);
    up.h2[1] = __floats2half2_rn(vz, vw);
    *(uint2*)(out + (size_t)node * 128 + l32 * 4) = up.u;
}

// ---------------- mean pool (fp16 in): per-(graph,part) float partials ----------------
__device__ __forceinline__ int lower_bound_i(const int* __restrict__ arr, int n, int key) {
    int lo = 0, hi = n;
    while (lo < hi) {
        int mid = (lo + hi) >> 1;
        if (arr[mid] < key) lo = mid + 1; else hi = mid;
    }
    return lo;
}

__global__ __launch_bounds__(256) void k_pool(const __half* __restrict__ h, const int* __restrict__ batch,
                                              float* __restrict__ pp, float* __restrict__ cnt) {
    int g = blockIdx.x;
    int part = blockIdx.y;
    int lo = lower_bound_i(batch, N_NODES, g);
    int hi = lower_bound_i(batch, N_NODES, g + 1);
    int num = hi - lo;
    if (part == 0 && threadIdx.x == 0) cnt[g] = (float)num;
    int chunk = (num + POOL_PARTS - 1) / POOL_PARTS;
    int a = lo + part * chunk;
    int b = min(a + chunk, hi);
    int c2 = threadIdx.x & 63;
    int sub = threadIdx.x >> 6;
    const __half2* __restrict__ h2 = (const __half2*)h;
    float2 acc = make_float2(0.f, 0.f);
    for (int node = a + sub; node < b; node += 4) {
        float2 v = __half22float2(h2[(size_t)node * 64 + c2]);
        acc.x += v.x; acc.y += v.y;
    }
    __shared__ float2 tmp[256];
    tmp[threadIdx.x] = acc;
    __syncthreads();
    if (sub == 0) {
        float2 s;
        s.x = tmp[c2].x + tmp[c2 + 64].x + tmp[c2 + 128].x + tmp[c2 + 192].x;
        s.y = tmp[c2].y + tmp[c2 + 64].y + tmp[c2 + 128].y + tmp[c2 + 192].y;
        ((float2*)pp)[((size_t)g * POOL_PARTS + part) * 64 + c2] = s;
    }
}

// ---------------- final MLP (reduces pool parts) ----------------
__global__ __launch_bounds__(128) void k_mlp(const float* __restrict__ pp1, const float* __restrict__ pp2,
                                             const float* __restrict__ cnt1, const float* __restrict__ cnt2,
                                             const float* __restrict__ lin1W, const float* __restrict__ lin1b,
                                             const float* __restrict__ lin2W, const float* __restrict__ lin2b,
                                             float* __restrict__ out) {
    int g = blockIdx.x;
    int c = threadIdx.x;
    __shared__ float cat[2 * D];
    float s1 = 0.f, s2 = 0.f;
#pragma unroll
    for (int p = 0; p < POOL_PARTS; p++) {
        s1 += pp1[((size_t)g * POOL_PARTS + p) * D + c];
        s2 += pp2[((size_t)g * POOL_PARTS + p) * D + c];
    }
    cat[c] = s1 / fmaxf(cnt1[g], 1.0f);
    cat[c + D] = s2 / fmaxf(cnt2[g], 1.0f);
    __syncthreads();
    float acc = lin1b[c];
#pragma unroll 8
    for (int k = 0; k < 2 * D; k++) acc += cat[k] * lin1W[k * D + c];
    acc = fmaxf(acc, 0.0f);
    float v = acc * lin2W[c];
#pragma unroll
    for (int off = 32; off > 0; off >>= 1) v += __shfl_down(v, off, 64);
    __shared__ float wsum[2];
    if ((c & 63) == 0) wsum[c >> 6] = v;
    __syncthreads();
    if (c == 0) out[g] = wsum[0] + wsum[1] + lin2b[0];
}

extern "C" void kernel_launch(void* const* d_in, const int* in_sizes, int n_in,
                              void* d_out, int out_size, void* d_ws, size_t ws_size,
                              hipStream_t stream) {
    const float* xs[2]      = {(const float*)d_in[0], (const float*)d_in[3]};
    const int*   eis[2]     = {(const int*)d_in[1], (const int*)d_in[4]};
    const int*   batches[2] = {(const int*)d_in[2], (const int*)d_in[5]};
    const float* W0[2] = {(const float*)d_in[6],  (const float*)d_in[10]};
    const float* b0[2] = {(const float*)d_in[7],  (const float*)d_in[11]};
    const float* W1[2] = {(const float*)d_in[8],  (const float*)d_in[12]};
    const float* b1[2] = {(const float*)d_in[9],  (const float*)d_in[13]};
    const float* lin1W = (const float*)d_in[14];
    const float* lin1b = (const float*)d_in[15];
    const float* lin2W = (const float*)d_in[16];
    const float* lin2b = (const float*)d_in[17];
    float* out = (float*)d_out;

    __half* WtH = (__half*)d_ws;                          // 65536 halves (128 KB)
    __half* ACT = WtH + 65536;                            // N*D halves
    unsigned char* H8 = (unsigned char*)(ACT + (size_t)N_NODES * D);  // N*128 bytes
    int*    cnti = (int*)(H8 + (size_t)N_NODES * 128);    // NPAD ints
    int*    gcnt0 = cnti + NPAD;                          // 196
    int*    gcnt1 = gcnt0 + BUCKETS;                      // 196
    int*    ocnt0 = gcnt1 + BUCKETS;                      // 1
    int*    ocnt1 = ocnt0 + 1;                            // 1 (+pad)
    int2*   ovf  = (int2*)(gcnt0 + 400);                  // OVF_CAP pairs
    unsigned short* ell = (unsigned short*)(ovf + OVF_CAP);   // NPAD*ELLW ushorts
    int2*   bucketed = (int2*)(ell + (size_t)NPAD * ELLW);    // BUCKETS*BCAP pairs
    float*  pp1  = (float*)(bucketed + (size_t)BUCKETS * BCAP);
    float*  pp2  = pp1 + (size_t)N_GRAPHS * POOL_PARTS * D;
    float*  cnt1 = pp2 + (size_t)N_GRAPHS * POOL_PARTS * D;
    float*  cnt2 = cnt1 + N_GRAPHS;
    int*    gcnts[2] = {gcnt0, gcnt1};
    int*    ocnts[2] = {ocnt0, ocnt1};
    float*  pps[2]   = {pp1, pp2};
    float*  cnts[2]  = {cnt1, cnt2};

    dim3 b256(256);
    int partBlocks = (N_EDGES + EPB - 1) / EPB;  // 196
    int gemmBlocks = (N_NODES + 63) / 64;        // 782
    int aggBlocks  = N_NODES / 8;                // 6250

    k_prep<<<4, b256, 0, stream>>>(W0[0], W1[0], W0[1], W1[1], WtH);
    hipMemsetAsync(gcnt0, 0, 400 * sizeof(int), stream);

    for (int br = 0; br < 2; br++) {
        const int* srcp = eis[br];
        const int* dstp = eis[br] + N_EDGES;

        k_part<<<partBlocks, b256, 0, stream>>>(srcp, dstp, gcnts[br], bucketed);
        k_build<<<BUCKETS, b256, 0, stream>>>(gcnts[br], bucketed, cnti, ell, ovf, ocnts[br]);

        k_gemm<false><<<gemmBlocks, b256, 0, stream>>>(xs[br], WtH + (size_t)(br * 2 + 0) * 16384, cnti, H8);
        k_agg<<<aggBlocks, b256, 0, stream>>>(cnti, ell, ovf, ocnts[br], H8, b0[br], ACT);
        k_gemm<true><<<gemmBlocks, b256, 0, stream>>>(ACT, WtH + (size_t)(br * 2 + 1) * 16384, cnti, H8);
        k_agg<<<aggBlocks, b256, 0, stream>>>(cnti, ell, ovf, ocnts[br], H8, b1[br], ACT);

        k_pool<<<dim3(N_GRAPHS, POOL_PARTS), b256, 0, stream>>>(ACT, batches[br], pps[br], cnts[br]);
    }
    k_mlp<<<N_GRAPHS, dim3(128), 0, stream>>>(pp1, pp2, cnt1, cnt2, lin1W, lin1b, lin2W, lin2b, out);
}